// Round 3
// baseline (542.181 us; speedup 1.0000x reference)
//
#include <hip/hip_runtime.h>
#include <stdint.h>

// ---------------- problem constants ----------------
#define TOK    4096
#define DMODEL 1024
#define FDIM   2048
#define NEXP   8
#define MAXP   10240           // 2*TOK + 8*256 worst-case segment padding
#define MAXT   40              // MAXP / 256 row tiles
#define OUT_MAIN (TOK * DMODEL)

// meta int indices
#define IDX_NT  24
#define IDX_TE  32
#define IDX_TR  112

// ws byte offsets
#define OFF_META 0
#define OFF_TKW  33792
#define OFF_PTOK 66560
#define OFF_PW   107520
#define OFF_XG   148480            // [MAXP][1024] bf16
#define OFF_H    21120000          // [MAXP][2048] bf16
#define OFF_WGB  63063040          // [E][F][D] bf16
#define OFF_WUB  96617472          // [E][F][D] bf16
#define OFF_WDB  130171904         // [E][D][F] bf16
#define OFF_PV   OFF_WGB           // [MAXP][1024] fp32 — aliases wgb+wub (dead after k_gu)
#define OFF_RPOS 163726336
#define WS_NEED  163759104

typedef __attribute__((ext_vector_type(8)))  __bf16 bf16x8;
typedef __attribute__((ext_vector_type(8)))  unsigned short u16x8;
typedef __attribute__((ext_vector_type(4)))  unsigned short u16x4;
typedef __attribute__((ext_vector_type(16))) float f32x16;

__device__ __forceinline__ unsigned short f2bf(float f) {
  unsigned u = __builtin_bit_cast(unsigned, f);
  u += 0x7fffu + ((u >> 16) & 1u);          // RNE
  return (unsigned short)(u >> 16);
}

__device__ __forceinline__ void async_load16(const void* g, void* l) {
  __builtin_amdgcn_global_load_lds(
      (__attribute__((address_space(1))) void*)g,
      (__attribute__((address_space(3))) void*)l, 16, 0, 0);
}

__device__ __forceinline__ bf16x8 ld_frag(const unsigned short* p) {
  return __builtin_bit_cast(bf16x8, *(const u16x8*)p);
}

// ---------------- fused prep: 3x weight conv (fp32->bf16) + router ----------------
// blocks [0,24576): conv; [24576,25600): router logits with fp64 accumulate
__global__ void k_prep(const float* __restrict__ wg, const float* __restrict__ wu,
                       const float* __restrict__ wd, unsigned short* __restrict__ wgb,
                       unsigned short* __restrict__ wub, unsigned short* __restrict__ wdb,
                       const float* __restrict__ x, const float* __restrict__ gw,
                       float* __restrict__ logits, int pre) {
  int b = blockIdx.x;
  if (b < 24576) {
    if (!pre) return;
    const float* src; unsigned short* dst; int bb;
    if (b < 8192)       { src = wg; dst = wgb; bb = b; }
    else if (b < 16384) { src = wu; dst = wub; bb = b - 8192; }
    else                { src = wd; dst = wdb; bb = b - 16384; }
    size_t i = ((size_t)bb * 256 + threadIdx.x) * 8;
    float4 a = *(const float4*)(src + i);
    float4 c = *(const float4*)(src + i + 4);
    u16x8 v = {f2bf(a.x), f2bf(a.y), f2bf(a.z), f2bf(a.w),
               f2bf(c.x), f2bf(c.y), f2bf(c.z), f2bf(c.w)};
    *(u16x8*)(dst + i) = v;
    return;
  }
  int lane = threadIdx.x & 63;
  int t = (b - 24576) * 4 + (threadIdx.x >> 6);
  double acc[NEXP];
#pragma unroll
  for (int e = 0; e < NEXP; ++e) acc[e] = 0.0;
  const float* xp = x + (size_t)t * DMODEL;
  for (int i = 0; i < DMODEL / 64; ++i) {
    int d = i * 64 + lane;
    float xv = xp[d];
#pragma unroll
    for (int e = 0; e < NEXP; ++e) acc[e] += (double)xv * (double)gw[e * DMODEL + d];
  }
#pragma unroll
  for (int e = 0; e < NEXP; ++e) {
    double v = acc[e];
#pragma unroll
    for (int off = 32; off > 0; off >>= 1) v += __shfl_down(v, off, 64);
    if (lane == 0) logits[t * NEXP + e] = (float)v;
  }
}

// ---------------- fused routing + scan + scatter (single block, 1024 thr) ----------
__global__ __launch_bounds__(1024) void k_route2(
    const float* __restrict__ logits, int* __restrict__ meta,
    float* __restrict__ tk_w, int* __restrict__ ptok, float* __restrict__ pw,
    int* __restrict__ rpos) {
  __shared__ int cnt[NEXP], cur[NEXP], seg[NEXP];
  int tid = threadIdx.x;
  if (tid < NEXP) { cnt[tid] = 0; cur[tid] = 0; }
  for (int r = tid; r < MAXP; r += 1024) ptok[r] = -1;
  __syncthreads();
  int i1[4], i2[4]; float w1v[4], w2v[4];
#pragma unroll
  for (int j = 0; j < 4; ++j) {
    int t = tid + j * 1024;
    float s[NEXP];
#pragma unroll
    for (int e = 0; e < NEXP; ++e) s[e] = logits[t * NEXP + e];
    float max1 = s[0]; int ind1 = 0;
#pragma unroll
    for (int e = 1; e < NEXP; ++e) if (s[e] > max1) { max1 = s[e]; ind1 = e; }
    float sum1 = 0.f;
#pragma unroll
    for (int e = 0; e < NEXP; ++e) {
      float f = fmaxf(fabsf(s[e]), max1);
      if (!((max1 - s[e]) / f > 0.02f)) sum1 += expf(s[e] - max1);
    }
    float max2 = -3.4e38f; int ind2 = 0;
#pragma unroll
    for (int e = 0; e < NEXP; ++e) if (e != ind1 && s[e] > max2) { max2 = s[e]; ind2 = e; }
    float sum2 = 0.f;
#pragma unroll
    for (int e = 0; e < NEXP; ++e) {
      if (e == ind1) continue;
      float f = fmaxf(fabsf(s[e]), max2);
      if (!((max2 - s[e]) / f > 0.02f)) sum2 += expf(s[e] - max2);
    }
    i1[j] = ind1; i2[j] = ind2; w1v[j] = 1.f / sum1; w2v[j] = 1.f / sum2;
    atomicAdd(&cnt[ind1], 1);
    atomicAdd(&cnt[ind2], 1);
  }
  __syncthreads();
  if (tid == 0) {
    int off = 0, nt2 = 0;
    for (int e = 0; e < NEXP; ++e) {
      seg[e] = off;
      int tiles = (cnt[e] + 255) >> 8;
      for (int j = 0; j < tiles; ++j) {
        meta[IDX_TE + nt2] = e;
        meta[IDX_TR + nt2] = off + (j << 8);
        ++nt2;
      }
      off += tiles << 8;
    }
    meta[IDX_NT] = nt2;
  }
  __syncthreads();
#pragma unroll
  for (int j = 0; j < 4; ++j) {
    int t = tid + j * 1024;
    int e1 = i1[j];
    int p1 = atomicAdd(&cur[e1], 1);
    int r1 = seg[e1] + p1;
    ptok[r1] = t; pw[r1] = w1v[j]; rpos[2 * t] = r1; tk_w[2 * t] = w1v[j];
    int e2 = i2[j];
    int p2 = atomicAdd(&cur[e2], 1);
    int r2 = seg[e2] + p2;
    ptok[r2] = t; pw[r2] = w2v[j]; rpos[2 * t + 1] = r2; tk_w[2 * t + 1] = w2v[j];
  }
}

// ---------------- gather x rows (fp32 -> bf16) in pair order; pads -> 0 ------------
__global__ void k_gather(const float* __restrict__ x, const int* __restrict__ ptok,
                         unsigned short* __restrict__ xg) {
  int r = blockIdx.x;
  int t = ptok[r];
  int c = threadIdx.x << 2;
  unsigned short o0 = 0, o1 = 0, o2 = 0, o3 = 0;
  if (t >= 0) {
    float4 v = *(const float4*)(x + ((size_t)t << 10) + c);
    o0 = f2bf(v.x); o1 = f2bf(v.y); o2 = f2bf(v.z); o3 = f2bf(v.w);
  }
  u16x4 o = {o0, o1, o2, o3};
  *(u16x4*)(xg + ((size_t)r << 10) + c) = o;
}

// ---------------- fused gate+up GEMM, 32x32x16 MFMA -------------------------------
// tile: 256 rows x (128 gate cols + 128 up cols), BK=64, 512 thr / 8 waves.
// Counted-vmcnt pipeline (T4) + XCD-supertile scheduling (T1): physical block p
// runs on XCD p%8; we assign each XCD a contiguous y-range of 5 row-tiles x all
// 16 col-blocks (80 blocks, 640 = 8*80 bijective). A row-tiles (512 KB) and the
// expert's B panels then hit the XCD-local 4 MB L2 instead of streaming from L3.
template <bool PRE>
__global__ __launch_bounds__(512, 2) void k_gu(
    const unsigned short* __restrict__ xg,
    const float* __restrict__ wg32, const float* __restrict__ wu32,
    const unsigned short* __restrict__ wgb, const unsigned short* __restrict__ wub,
    unsigned short* __restrict__ h, const int* __restrict__ meta) {
  int p = blockIdx.x;
  int xcd = p & 7, slot = p >> 3;                 // 80 slots per XCD
  int bx = (slot / 40) * 8 + (slot & 7);          // x: two groups of 8
  int rt = xcd * 5 + ((slot % 40) >> 3);          // y: XCD-owned range of 5

  int nt = meta[IDX_NT];
  if (rt >= nt) return;
  int e = meta[IDX_TE + rt];
  int row0 = meta[IDX_TR + rt];
  int n0 = bx * 128;

  __shared__ __align__(16) unsigned short sA[2][16384];   // 256 rows x 64 k
  __shared__ __align__(16) unsigned short sBg[2][8192];   // 128 cols x 64 k
  __shared__ __align__(16) unsigned short sBu[2][8192];

  int tid = threadIdx.x, lane = tid & 63, w = tid >> 6;
  int wm = w & 1, wn = w >> 1;
  int l31 = lane & 31, lh = lane >> 5;

  f32x16 accg[4], accu[4];
#pragma unroll
  for (int m = 0; m < 4; ++m) {
#pragma unroll
    for (int r = 0; r < 16; ++r) { accg[m][r] = 0.f; accu[m][r] = 0.f; }
  }

  // A: wave w stages rows [w*32, w*32+32) -> chunks (w*4 + kq)
  const unsigned short* Abase =
      xg + (size_t)(row0 + w * 32 + l31) * DMODEL + lh * 8;
  // B: wave w stages chunks cb0=2w, cb1=2w+1 (chunk c = nsub*4 + kq)
  int cb0 = w * 2, cb1 = cb0 + 1;
  const unsigned short *G0, *G1, *U0, *U1;
  if constexpr (PRE) {
    const unsigned short* WgB = wgb + (size_t)e * FDIM * DMODEL;
    const unsigned short* WuB = wub + (size_t)e * FDIM * DMODEL;
    size_t o0 = (size_t)(n0 + ((cb0 >> 2) << 5) + l31) * DMODEL + ((cb0 & 3) << 4) + lh * 8;
    size_t o1 = (size_t)(n0 + ((cb1 >> 2) << 5) + l31) * DMODEL + ((cb1 & 3) << 4) + lh * 8;
    G0 = WgB + o0; G1 = WgB + o1; U0 = WuB + o0; U1 = WuB + o1;
  }
  const float* Wg = nullptr; const float* Wu = nullptr;
  if constexpr (!PRE) {
    Wg = wg32 + (size_t)e * FDIM * DMODEL;
    Wu = wu32 + (size_t)e * FDIM * DMODEL;
  }

  auto stage = [&](int buf, int ks) {
    int k0 = ks * 64;
    async_load16(Abase + k0,      &sA[buf][(w * 4 + 0) * 512]);
    async_load16(Abase + k0 + 16, &sA[buf][(w * 4 + 1) * 512]);
    async_load16(Abase + k0 + 32, &sA[buf][(w * 4 + 2) * 512]);
    async_load16(Abase + k0 + 48, &sA[buf][(w * 4 + 3) * 512]);
    if constexpr (PRE) {
      async_load16(G0 + k0, &sBg[buf][cb0 * 512]);
      async_load16(G1 + k0, &sBg[buf][cb1 * 512]);
      async_load16(U0 + k0, &sBu[buf][cb0 * 512]);
      async_load16(U1 + k0, &sBu[buf][cb1 * 512]);
    } else {
#pragma unroll
      for (int i2 = 0; i2 < 2; ++i2) {
        int tau = tid + 512 * i2;
        int c = tau >> 6, l = tau & 63;
        int nrow = n0 + ((c >> 2) << 5) + (l & 31);
        int kk = k0 + ((c & 3) << 4) + ((l >> 5) << 3);
        const float* sg = Wg + (size_t)nrow * DMODEL + kk;
        const float* su = Wu + (size_t)nrow * DMODEL + kk;
        float4 g0 = *(const float4*)sg;
        float4 g1 = *(const float4*)(sg + 4);
        float4 u0 = *(const float4*)su;
        float4 u1 = *(const float4*)(su + 4);
        u16x8 vg = {f2bf(g0.x), f2bf(g0.y), f2bf(g0.z), f2bf(g0.w),
                    f2bf(g1.x), f2bf(g1.y), f2bf(g1.z), f2bf(g1.w)};
        u16x8 vu = {f2bf(u0.x), f2bf(u0.y), f2bf(u0.z), f2bf(u0.w),
                    f2bf(u1.x), f2bf(u1.y), f2bf(u1.z), f2bf(u1.w)};
        *(u16x8*)&sBg[buf][c * 512 + l * 8] = vg;
        *(u16x8*)&sBu[buf][c * 512 + l * 8] = vu;
      }
    }
  };

  auto compute = [&](int buf) {
#pragma unroll
    for (int kq = 0; kq < 4; ++kq) {
      bf16x8 a0 = ld_frag(&sA[buf][((wm * 4 + 0) * 4 + kq) * 512 + lane * 8]);
      bf16x8 a1 = ld_frag(&sA[buf][((wm * 4 + 1) * 4 + kq) * 512 + lane * 8]);
      bf16x8 a2 = ld_frag(&sA[buf][((wm * 4 + 2) * 4 + kq) * 512 + lane * 8]);
      bf16x8 a3 = ld_frag(&sA[buf][((wm * 4 + 3) * 4 + kq) * 512 + lane * 8]);
      bf16x8 vg = ld_frag(&sBg[buf][(wn * 4 + kq) * 512 + lane * 8]);
      bf16x8 vu = ld_frag(&sBu[buf][(wn * 4 + kq) * 512 + lane * 8]);
      accg[0] = __builtin_amdgcn_mfma_f32_32x32x16_bf16(a0, vg, accg[0], 0, 0, 0);
      accg[1] = __builtin_amdgcn_mfma_f32_32x32x16_bf16(a1, vg, accg[1], 0, 0, 0);
      accg[2] = __builtin_amdgcn_mfma_f32_32x32x16_bf16(a2, vg, accg[2], 0, 0, 0);
      accg[3] = __builtin_amdgcn_mfma_f32_32x32x16_bf16(a3, vg, accg[3], 0, 0, 0);
      accu[0] = __builtin_amdgcn_mfma_f32_32x32x16_bf16(a0, vu, accu[0], 0, 0, 0);
      accu[1] = __builtin_amdgcn_mfma_f32_32x32x16_bf16(a1, vu, accu[1], 0, 0, 0);
      accu[2] = __builtin_amdgcn_mfma_f32_32x32x16_bf16(a2, vu, accu[2], 0, 0, 0);
      accu[3] = __builtin_amdgcn_mfma_f32_32x32x16_bf16(a3, vu, accu[3], 0, 0, 0);
    }
  };

  int cur = 0;
  stage(0, 0);
  if constexpr (PRE) {
#pragma unroll 2
    for (int ks = 0; ks < DMODEL / 64; ++ks) {
      if (ks + 1 < DMODEL / 64) {
        stage(cur ^ 1, ks + 1);
        asm volatile("s_waitcnt vmcnt(8)" ::: "memory");   // tile ks landed; ks+1 in flight
      } else {
        asm volatile("s_waitcnt vmcnt(0)" ::: "memory");   // final tile
      }
      __builtin_amdgcn_s_barrier();
      __builtin_amdgcn_s_setprio(1);
      compute(cur);
      __builtin_amdgcn_s_setprio(0);
      __builtin_amdgcn_s_barrier();                        // protect buf reuse; no drain
      cur ^= 1;
    }
  } else {
    __syncthreads();
    for (int ks = 0; ks < DMODEL / 64; ++ks) {
      if (ks + 1 < DMODEL / 64) stage(cur ^ 1, ks + 1);
      compute(cur);
      __syncthreads();
      cur ^= 1;
    }
  }

  // epilogue: C/D layout col=lane&31, row=(r&3)+8*(r>>2)+4*lh
  int col = n0 + wn * 32 + l31;
#pragma unroll
  for (int m = 0; m < 4; ++m) {
#pragma unroll
    for (int r = 0; r < 16; ++r) {
      int lrow = wm * 128 + m * 32 + (r & 3) + ((r >> 2) << 3) + lh * 4;
      float gv = accg[m][r], uv = accu[m][r];
      float hv = gv * uv / (1.f + __expf(-gv));
      h[(size_t)(row0 + lrow) * FDIM + col] = f2bf(hv);
    }
  }
}

// ---------------- down GEMM: pv = h @ Wd^T, tile 256x128, BK=64, counted vmcnt -----
// Same XCD-supertile mapping: XCD c owns row-tiles [5c,5c+5) x all 8 col-blocks
// (320 = 8*40 bijective). k_gu on XCD c WROTE exactly those h rows -> L2 hits.
template <bool PRE>
__global__ __launch_bounds__(512, 2) void k_down(
    const unsigned short* __restrict__ h, const float* __restrict__ wd32,
    const unsigned short* __restrict__ wdb, float* __restrict__ out,
    float* __restrict__ pv, const int* __restrict__ meta,
    const int* __restrict__ ptok, const float* __restrict__ pw) {
  int p = blockIdx.x;
  int xcd = p & 7, slot = p >> 3;                 // 40 slots per XCD
  int bx = slot & 7;
  int rt = xcd * 5 + (slot >> 3);

  int nt = meta[IDX_NT];
  if (rt >= nt) return;
  int e = meta[IDX_TE + rt];
  int row0 = meta[IDX_TR + rt];
  int d0 = bx * 128;

  __shared__ __align__(16) unsigned short sA[2][16384];   // 256 rows x 64 k
  __shared__ __align__(16) unsigned short sB[2][8192];    // 128 cols x 64 k
  __shared__ int stok[256];
  __shared__ float sw_[256];

  int tid = threadIdx.x, lane = tid & 63, w = tid >> 6;
  int wm = w & 1, wn = w >> 1;
  int l31 = lane & 31, lh = lane >> 5;

  if constexpr (!PRE) {
    if (tid < 256) { stok[tid] = ptok[row0 + tid]; sw_[tid] = pw[row0 + tid]; }
  }

  f32x16 acc[4];
#pragma unroll
  for (int m = 0; m < 4; ++m) {
#pragma unroll
    for (int r = 0; r < 16; ++r) acc[m][r] = 0.f;
  }

  const unsigned short* Abase =
      h + (size_t)(row0 + w * 32 + l31) * FDIM + lh * 8;
  int cb0 = w * 2, cb1 = cb0 + 1;
  const unsigned short *D0, *D1;
  if constexpr (PRE) {
    const unsigned short* WdB = wdb + (size_t)e * DMODEL * FDIM;
    D0 = WdB + (size_t)(d0 + ((cb0 >> 2) << 5) + l31) * FDIM + ((cb0 & 3) << 4) + lh * 8;
    D1 = WdB + (size_t)(d0 + ((cb1 >> 2) << 5) + l31) * FDIM + ((cb1 & 3) << 4) + lh * 8;
  }
  const float* Wd = nullptr;
  if constexpr (!PRE) Wd = wd32 + (size_t)e * DMODEL * FDIM;

  auto stage = [&](int buf, int ks) {
    int k0 = ks * 64;
    async_load16(Abase + k0,      &sA[buf][(w * 4 + 0) * 512]);
    async_load16(Abase + k0 + 16, &sA[buf][(w * 4 + 1) * 512]);
    async_load16(Abase + k0 + 32, &sA[buf][(w * 4 + 2) * 512]);
    async_load16(Abase + k0 + 48, &sA[buf][(w * 4 + 3) * 512]);
    if constexpr (PRE) {
      async_load16(D0 + k0, &sB[buf][cb0 * 512]);
      async_load16(D1 + k0, &sB[buf][cb1 * 512]);
    } else {
#pragma unroll
      for (int i2 = 0; i2 < 2; ++i2) {
        int tau = tid + 512 * i2;
        int c = tau >> 6, l = tau & 63;
        int drow = d0 + ((c >> 2) << 5) + (l & 31);
        int kk = k0 + ((c & 3) << 4) + ((l >> 5) << 3);
        const float* sd = Wd + (size_t)drow * FDIM + kk;
        float4 b0 = *(const float4*)sd;
        float4 b1 = *(const float4*)(sd + 4);
        u16x8 vb = {f2bf(b0.x), f2bf(b0.y), f2bf(b0.z), f2bf(b0.w),
                    f2bf(b1.x), f2bf(b1.y), f2bf(b1.z), f2bf(b1.w)};
        *(u16x8*)&sB[buf][c * 512 + l * 8] = vb;
      }
    }
  };

  auto compute = [&](int buf) {
#pragma unroll
    for (int kq = 0; kq < 4; ++kq) {
      bf16x8 a0 = ld_frag(&sA[buf][((wm * 4 + 0) * 4 + kq) * 512 + lane * 8]);
      bf16x8 a1 = ld_frag(&sA[buf][((wm * 4 + 1) * 4 + kq) * 512 + lane * 8]);
      bf16x8 a2 = ld_frag(&sA[buf][((wm * 4 + 2) * 4 + kq) * 512 + lane * 8]);
      bf16x8 a3 = ld_frag(&sA[buf][((wm * 4 + 3) * 4 + kq) * 512 + lane * 8]);
      bf16x8 vb = ld_frag(&sB[buf][(wn * 4 + kq) * 512 + lane * 8]);
      acc[0] = __builtin_amdgcn_mfma_f32_32x32x16_bf16(a0, vb, acc[0], 0, 0, 0);
      acc[1] = __builtin_amdgcn_mfma_f32_32x32x16_bf16(a1, vb, acc[1], 0, 0, 0);
      acc[2] = __builtin_amdgcn_mfma_f32_32x32x16_bf16(a2, vb, acc[2], 0, 0, 0);
      acc[3] = __builtin_amdgcn_mfma_f32_32x32x16_bf16(a3, vb, acc[3], 0, 0, 0);
    }
  };

  int cur = 0;
  stage(0, 0);
  if constexpr (PRE) {
#pragma unroll 2
    for (int ks = 0; ks < FDIM / 64; ++ks) {
      if (ks + 1 < FDIM / 64) {
        stage(cur ^ 1, ks + 1);
        asm volatile("s_waitcnt vmcnt(6)" ::: "memory");   // tile ks landed; ks+1 in flight
      } else {
        asm volatile("s_waitcnt vmcnt(0)" ::: "memory");
      }
      __builtin_amdgcn_s_barrier();
      __builtin_amdgcn_s_setprio(1);
      compute(cur);
      __builtin_amdgcn_s_setprio(0);
      __builtin_amdgcn_s_barrier();
      cur ^= 1;
    }
  } else {
    __syncthreads();
    for (int ks = 0; ks < FDIM / 64; ++ks) {
      if (ks + 1 < FDIM / 64) stage(cur ^ 1, ks + 1);
      compute(cur);
      __syncthreads();
      cur ^= 1;
    }
  }

  int col = d0 + wn * 32 + l31;
#pragma unroll
  for (int m = 0; m < 4; ++m) {
#pragma unroll
    for (int r = 0; r < 16; ++r) {
      int lrow = wm * 128 + m * 32 + (r & 3) + ((r >> 2) << 3) + lh * 4;
      if constexpr (PRE) {
        pv[(size_t)(row0 + lrow) * DMODEL + col] = acc[m][r];
      } else {
        int t = stok[lrow];
        if (t >= 0) atomicAdd(&out[(size_t)t * DMODEL + col], acc[m][r] * sw_[lrow]);
      }
    }
  }
}

// ---------------- combine: out[t] = w1*pv[r1] + w2*pv[r2] --------------------------
__global__ void k_combine(const float* __restrict__ pv, const int* __restrict__ rpos,
                          const float* __restrict__ tkw, float* __restrict__ out) {
  int t = blockIdx.x;
  int r1 = rpos[2 * t], r2 = rpos[2 * t + 1];
  float w1 = tkw[2 * t], w2 = tkw[2 * t + 1];
  int c = threadIdx.x << 2;
  float4 a = *(const float4*)(pv + (size_t)r1 * DMODEL + c);
  float4 b = *(const float4*)(pv + (size_t)r2 * DMODEL + c);
  float4 o;
  o.x = w1 * a.x + w2 * b.x;
  o.y = w1 * a.y + w2 * b.y;
  o.z = w1 * a.z + w2 * b.z;
  o.w = w1 * a.w + w2 * b.w;
  *(float4*)(out + (size_t)t * DMODEL + c) = o;
}

// ---------------- launch ----------------
extern "C" void kernel_launch(void* const* d_in, const int* in_sizes, int n_in,
                              void* d_out, int out_size, void* d_ws, size_t ws_size,
                              hipStream_t stream) {
  const float* x  = (const float*)d_in[0];
  const float* gw = (const float*)d_in[1];
  const float* wg = (const float*)d_in[2];
  const float* wu = (const float*)d_in[3];
  const float* wd = (const float*)d_in[4];
  float* out = (float*)d_out;
  float* logits = out + OUT_MAIN;

  char* wsb = (char*)d_ws;
  int* meta = (int*)(wsb + OFF_META);
  float* tk_w = (float*)(wsb + OFF_TKW);
  int* ptok = (int*)(wsb + OFF_PTOK);
  float* pw = (float*)(wsb + OFF_PW);
  unsigned short* xg = (unsigned short*)(wsb + OFF_XG);
  unsigned short* h = (unsigned short*)(wsb + OFF_H);
  unsigned short* wgb = (unsigned short*)(wsb + OFF_WGB);
  unsigned short* wub = (unsigned short*)(wsb + OFF_WUB);
  unsigned short* wdb = (unsigned short*)(wsb + OFF_WDB);
  float* pv = (float*)(wsb + OFF_PV);
  int* rpos = (int*)(wsb + OFF_RPOS);

  bool pre = ws_size >= (size_t)WS_NEED;
  if (!pre) hipMemsetAsync(out, 0, (size_t)OUT_MAIN * sizeof(float), stream);

  k_prep<<<25600, 256, 0, stream>>>(wg, wu, wd, wgb, wub, wdb, x, gw, logits, (int)pre);
  k_route2<<<1, 1024, 0, stream>>>(logits, meta, tk_w, ptok, pw, rpos);
  k_gather<<<MAXP, 256, 0, stream>>>(x, ptok, xg);
  if (pre) {
    k_gu<true><<<(FDIM / 128) * MAXT, 512, 0, stream>>>(xg, wg, wu, wgb, wub, h, meta);
    k_down<true><<<(DMODEL / 128) * MAXT, 512, 0, stream>>>(h, wd, wdb, out, pv, meta, ptok, pw);
    k_combine<<<TOK, 256, 0, stream>>>(pv, rpos, tk_w, out);
  } else {
    k_gu<false><<<(FDIM / 128) * MAXT, 512, 0, stream>>>(xg, wg, wu, wgb, wub, h, meta);
    k_down<false><<<(DMODEL / 128) * MAXT, 512, 0, stream>>>(h, wd, wdb, out, pv, meta, ptok, pw);
  }
}

// Round 4
// 501.353 us; speedup vs baseline: 1.0814x; 1.0814x over previous
//
#include <hip/hip_runtime.h>
#include <stdint.h>

// ---------------- problem constants ----------------
#define TOK    4096
#define DMODEL 1024
#define FDIM   2048
#define NEXP   8
#define MAXP   10240           // 2*TOK + 8*256 worst-case segment padding
#define MAXT   40              // MAXP / 256 row tiles
#define OUT_MAIN (TOK * DMODEL)

// meta int indices
#define IDX_NT  24
#define IDX_TE  32
#define IDX_TR  112

// ws byte offsets (all sizes unchanged; layouts inside are chunk-packed now)
#define OFF_META 0
#define OFF_TKW  33792
#define OFF_PTOK 66560
#define OFF_PW   107520
#define OFF_XG   148480            // xg2: chunk-packed [MAXT][16ks][8msub][4kq][64lane][8] bf16
#define OFF_H    21120000          // h2:  chunk-packed [MAXT][32ks][8msub][4kq][64lane][8] bf16
#define OFF_WGB  63063040          // wgb2: [E][16bx][16ks][16c][64lane][8] bf16
#define OFF_WUB  96617472          // wub2: same
#define OFF_WDB  130171904         // wdb2: [E][8bx][32ks][16c][64lane][8] bf16
#define OFF_PV   OFF_WGB           // [MAXP][1024] fp32 — aliases wgb+wub (dead after k_gu)
#define OFF_RPOS 163726336
#define WS_NEED  163759104

typedef __attribute__((ext_vector_type(8)))  __bf16 bf16x8;
typedef __attribute__((ext_vector_type(8)))  unsigned short u16x8;
typedef __attribute__((ext_vector_type(4)))  unsigned short u16x4;
typedef __attribute__((ext_vector_type(16))) float f32x16;

__device__ __forceinline__ unsigned short f2bf(float f) {
  unsigned u = __builtin_bit_cast(unsigned, f);
  u += 0x7fffu + ((u >> 16) & 1u);          // RNE
  return (unsigned short)(u >> 16);
}

__device__ __forceinline__ void async_load16(const void* g, void* l) {
  __builtin_amdgcn_global_load_lds(
      (__attribute__((address_space(1))) void*)g,
      (__attribute__((address_space(3))) void*)l, 16, 0, 0);
}

__device__ __forceinline__ bf16x8 ld_frag(const unsigned short* p) {
  return __builtin_bit_cast(bf16x8, *(const u16x8*)p);
}

// ---------------- fused prep: 3x weight conv (fp32->bf16, CHUNK-PACKED) + router ---
// blocks [0,40960): conv, one block per weight row; [40960,41984): router logits.
// Chunk layout (matches MFMA fragment staging): value W[row][k] lands at
//   panel(e,bx) ++ [ks][c = sub*4+kq][lane = l31 + 32*lh][j]
// with row = bx*128 + sub*32 + l31, k = ks*64 + kq*16 + lh*8 + j.
__global__ void k_prep(const float* __restrict__ wg, const float* __restrict__ wu,
                       const float* __restrict__ wd, unsigned short* __restrict__ wgb,
                       unsigned short* __restrict__ wub, unsigned short* __restrict__ wdb,
                       const float* __restrict__ x, const float* __restrict__ gw,
                       float* __restrict__ logits, int pre) {
  int b = blockIdx.x;
  if (b < 40960) {
    if (!pre) return;
    if (b < 32768) {                     // wg / wu rows: K=1024, 128 pieces
      const float* src = (b < 16384) ? wg : wu;
      unsigned short* dst = (b < 16384) ? wgb : wub;
      int gr = b & 16383;
      int e = gr >> 11, n = gr & 2047;
      int bx = n >> 7, nsub = (n >> 5) & 3, l31 = n & 31;
      int p = threadIdx.x;
      if (p < 128) {
        int ks = p >> 3, kq = (p >> 1) & 3, lh = p & 1;
        const float* s = src + (size_t)gr * 1024 + p * 8;
        float4 a = *(const float4*)s;
        float4 c = *(const float4*)(s + 4);
        u16x8 v = {f2bf(a.x), f2bf(a.y), f2bf(a.z), f2bf(a.w),
                   f2bf(c.x), f2bf(c.y), f2bf(c.z), f2bf(c.w)};
        size_t off = ((((size_t)(e * 16 + bx) * 16 + ks) * 16) + nsub * 4 + kq) * 512 +
                     (size_t)(l31 + 32 * lh) * 8;
        *(u16x8*)(dst + off) = v;
      }
    } else {                             // wd rows: K=2048, 256 pieces
      int gr = b - 32768;
      int e = gr >> 10, d = gr & 1023;
      int bx = d >> 7, nsub = (d >> 5) & 3, l31 = d & 31;
      int p = threadIdx.x;
      int ks = p >> 3, kq = (p >> 1) & 3, lh = p & 1;
      const float* s = wd + (size_t)gr * 2048 + p * 8;
      float4 a = *(const float4*)s;
      float4 c = *(const float4*)(s + 4);
      u16x8 v = {f2bf(a.x), f2bf(a.y), f2bf(a.z), f2bf(a.w),
                 f2bf(c.x), f2bf(c.y), f2bf(c.z), f2bf(c.w)};
      size_t off = ((((size_t)(e * 8 + bx) * 32 + ks) * 16) + nsub * 4 + kq) * 512 +
                   (size_t)(l31 + 32 * lh) * 8;
      *(u16x8*)(wdb + off) = v;
    }
    return;
  }
  int lane = threadIdx.x & 63;
  int t = (b - 40960) * 4 + (threadIdx.x >> 6);
  double acc[NEXP];
#pragma unroll
  for (int e = 0; e < NEXP; ++e) acc[e] = 0.0;
  const float* xp = x + (size_t)t * DMODEL;
  for (int i = 0; i < DMODEL / 64; ++i) {
    int d = i * 64 + lane;
    float xv = xp[d];
#pragma unroll
    for (int e = 0; e < NEXP; ++e) acc[e] += (double)xv * (double)gw[e * DMODEL + d];
  }
#pragma unroll
  for (int e = 0; e < NEXP; ++e) {
    double v = acc[e];
#pragma unroll
    for (int off = 32; off > 0; off >>= 1) v += __shfl_down(v, off, 64);
    if (lane == 0) logits[t * NEXP + e] = (float)v;
  }
}

// ---------------- fused routing + scan + scatter (single block, 1024 thr) ----------
__global__ __launch_bounds__(1024) void k_route2(
    const float* __restrict__ logits, int* __restrict__ meta,
    float* __restrict__ tk_w, int* __restrict__ ptok, float* __restrict__ pw,
    int* __restrict__ rpos) {
  __shared__ int cnt[NEXP], cur[NEXP], seg[NEXP];
  int tid = threadIdx.x;
  if (tid < NEXP) { cnt[tid] = 0; cur[tid] = 0; }
  for (int r = tid; r < MAXP; r += 1024) ptok[r] = -1;
  __syncthreads();
  int i1[4], i2[4]; float w1v[4], w2v[4];
#pragma unroll
  for (int j = 0; j < 4; ++j) {
    int t = tid + j * 1024;
    float s[NEXP];
#pragma unroll
    for (int e = 0; e < NEXP; ++e) s[e] = logits[t * NEXP + e];
    float max1 = s[0]; int ind1 = 0;
#pragma unroll
    for (int e = 1; e < NEXP; ++e) if (s[e] > max1) { max1 = s[e]; ind1 = e; }
    float sum1 = 0.f;
#pragma unroll
    for (int e = 0; e < NEXP; ++e) {
      float f = fmaxf(fabsf(s[e]), max1);
      if (!((max1 - s[e]) / f > 0.02f)) sum1 += expf(s[e] - max1);
    }
    float max2 = -3.4e38f; int ind2 = 0;
#pragma unroll
    for (int e = 0; e < NEXP; ++e) if (e != ind1 && s[e] > max2) { max2 = s[e]; ind2 = e; }
    float sum2 = 0.f;
#pragma unroll
    for (int e = 0; e < NEXP; ++e) {
      if (e == ind1) continue;
      float f = fmaxf(fabsf(s[e]), max2);
      if (!((max2 - s[e]) / f > 0.02f)) sum2 += expf(s[e] - max2);
    }
    i1[j] = ind1; i2[j] = ind2; w1v[j] = 1.f / sum1; w2v[j] = 1.f / sum2;
    atomicAdd(&cnt[ind1], 1);
    atomicAdd(&cnt[ind2], 1);
  }
  __syncthreads();
  if (tid == 0) {
    int off = 0, nt2 = 0;
    for (int e = 0; e < NEXP; ++e) {
      seg[e] = off;
      int tiles = (cnt[e] + 255) >> 8;
      for (int j = 0; j < tiles; ++j) {
        meta[IDX_TE + nt2] = e;
        meta[IDX_TR + nt2] = off + (j << 8);
        ++nt2;
      }
      off += tiles << 8;
    }
    meta[IDX_NT] = nt2;
  }
  __syncthreads();
#pragma unroll
  for (int j = 0; j < 4; ++j) {
    int t = tid + j * 1024;
    int e1 = i1[j];
    int p1 = atomicAdd(&cur[e1], 1);
    int r1 = seg[e1] + p1;
    ptok[r1] = t; pw[r1] = w1v[j]; rpos[2 * t] = r1; tk_w[2 * t] = w1v[j];
    int e2 = i2[j];
    int p2 = atomicAdd(&cur[e2], 1);
    int r2 = seg[e2] + p2;
    ptok[r2] = t; pw[r2] = w2v[j]; rpos[2 * t + 1] = r2; tk_w[2 * t + 1] = w2v[j];
  }
}

// ---------------- gather x rows (fp32 -> bf16), CHUNK-PACKED; pads -> 0 ------------
// xg2: tile rt ++ [ks(16)][msub*4+kq][lane = l31+32*lh][j], row = rt*256+msub*32+l31,
// k = ks*64+kq*16+lh*8+j.  One block per padded row, 128 threads (one 16B piece each).
__global__ void k_gather(const float* __restrict__ x, const int* __restrict__ ptok,
                         unsigned short* __restrict__ xg) {
  int rr = blockIdx.x;
  int t = ptok[rr];
  int rt = rr >> 8, msub = (rr >> 5) & 7, l31 = rr & 31;
  int p = threadIdx.x;
  int ks = p >> 3, kq = (p >> 1) & 3, lh = p & 1;
  u16x8 v = {0, 0, 0, 0, 0, 0, 0, 0};
  if (t >= 0) {
    const float* s = x + ((size_t)t << 10) + p * 8;
    float4 a = *(const float4*)s;
    float4 c = *(const float4*)(s + 4);
    v = (u16x8){f2bf(a.x), f2bf(a.y), f2bf(a.z), f2bf(a.w),
                f2bf(c.x), f2bf(c.y), f2bf(c.z), f2bf(c.w)};
  }
  size_t off = (((size_t)(rt * 16 + ks) * 32) + msub * 4 + kq) * 512 +
               (size_t)(l31 + 32 * lh) * 8;
  *(u16x8*)(xg + off) = v;
}

// ---------------- fused gate+up GEMM, 32x32x16 MFMA -------------------------------
// tile: 256 rows x (128 gate cols + 128 up cols), BK=64, 512 thr / 8 waves.
// Counted-vmcnt pipeline (T4) + XCD supertile (T1). All global_load_lds sources are
// now CONTIGUOUS 1KB (chunk-packed global layouts) — full 64B lines, sequential,
// instead of 32 scattered 32B fragments per instruction (the round-0..3 bottleneck).
template <bool PRE>
__global__ __launch_bounds__(512, 2) void k_gu(
    const unsigned short* __restrict__ xg,
    const float* __restrict__ wg32, const float* __restrict__ wu32,
    const unsigned short* __restrict__ wgb, const unsigned short* __restrict__ wub,
    unsigned short* __restrict__ h, const int* __restrict__ meta) {
  int p = blockIdx.x;
  int xcd = p & 7, slot = p >> 3;                 // 80 slots per XCD
  int bx = (slot / 40) * 8 + (slot & 7);          // x: two groups of 8
  int rt = xcd * 5 + ((slot % 40) >> 3);          // y: XCD-owned range of 5

  int nt = meta[IDX_NT];
  if (rt >= nt) return;
  int e = meta[IDX_TE + rt];
  int row0 = meta[IDX_TR + rt];
  int n0 = bx * 128;

  __shared__ __align__(16) unsigned short sA[2][16384];   // 32 chunks (256 rows x 64 k)
  __shared__ __align__(16) unsigned short sBg[2][8192];   // 16 chunks (128 cols x 64 k)
  __shared__ __align__(16) unsigned short sBu[2][8192];

  int tid = threadIdx.x, lane = tid & 63, w = tid >> 6;
  int wm = w & 1, wn = w >> 1;
  int l31 = lane & 31, lh = lane >> 5;

  f32x16 accg[4], accu[4];
#pragma unroll
  for (int m = 0; m < 4; ++m) {
#pragma unroll
    for (int r = 0; r < 16; ++r) { accg[m][r] = 0.f; accu[m][r] = 0.f; }
  }

  // A chunks: global chunk (rt*16+ks)*32 + w*4 + kq, contiguous 1KB each.
  const unsigned short* A0 =
      xg + (((size_t)rt * 16) * 32 + w * 4) * 512 + (size_t)lane * 8;
  // B chunks: wave stages cb0=2w, cb1=2w+1 of the 16 per-ks chunks.
  int cb0 = w * 2, cb1 = cb0 + 1;
  const unsigned short *Bg0, *Bu0;
  if constexpr (PRE) {
    size_t pb = (((size_t)(e * 16 + bx) * 16) * 16 + cb0) * 512 + (size_t)lane * 8;
    Bg0 = wgb + pb;
    Bu0 = wub + pb;
  }
  const float* Wg = nullptr; const float* Wu = nullptr;
  if constexpr (!PRE) {
    Wg = wg32 + (size_t)e * FDIM * DMODEL;
    Wu = wu32 + (size_t)e * FDIM * DMODEL;
  }

  auto stage = [&](int buf, int ks) {
    size_t ao = (size_t)ks * 16384;                 // 32 chunks/ks * 512
    async_load16(A0 + ao,        &sA[buf][(w * 4 + 0) * 512]);
    async_load16(A0 + ao + 512,  &sA[buf][(w * 4 + 1) * 512]);
    async_load16(A0 + ao + 1024, &sA[buf][(w * 4 + 2) * 512]);
    async_load16(A0 + ao + 1536, &sA[buf][(w * 4 + 3) * 512]);
    if constexpr (PRE) {
      size_t bo = (size_t)ks * 8192;                // 16 chunks/ks * 512
      async_load16(Bg0 + bo,       &sBg[buf][cb0 * 512]);
      async_load16(Bg0 + bo + 512, &sBg[buf][cb1 * 512]);
      async_load16(Bu0 + bo,       &sBu[buf][cb0 * 512]);
      async_load16(Bu0 + bo + 512, &sBu[buf][cb1 * 512]);
    } else {
      int k0 = ks * 64;
#pragma unroll
      for (int i2 = 0; i2 < 2; ++i2) {
        int tau = tid + 512 * i2;
        int c = tau >> 6, l = tau & 63;
        int nrow = n0 + ((c >> 2) << 5) + (l & 31);
        int kk = k0 + ((c & 3) << 4) + ((l >> 5) << 3);
        const float* sg = Wg + (size_t)nrow * DMODEL + kk;
        const float* su = Wu + (size_t)nrow * DMODEL + kk;
        float4 g0 = *(const float4*)sg;
        float4 g1 = *(const float4*)(sg + 4);
        float4 u0 = *(const float4*)su;
        float4 u1 = *(const float4*)(su + 4);
        u16x8 vg = {f2bf(g0.x), f2bf(g0.y), f2bf(g0.z), f2bf(g0.w),
                    f2bf(g1.x), f2bf(g1.y), f2bf(g1.z), f2bf(g1.w)};
        u16x8 vu = {f2bf(u0.x), f2bf(u0.y), f2bf(u0.z), f2bf(u0.w),
                    f2bf(u1.x), f2bf(u1.y), f2bf(u1.z), f2bf(u1.w)};
        *(u16x8*)&sBg[buf][c * 512 + l * 8] = vg;
        *(u16x8*)&sBu[buf][c * 512 + l * 8] = vu;
      }
    }
  };

  auto compute = [&](int buf) {
#pragma unroll
    for (int kq = 0; kq < 4; ++kq) {
      bf16x8 a0 = ld_frag(&sA[buf][((wm * 4 + 0) * 4 + kq) * 512 + lane * 8]);
      bf16x8 a1 = ld_frag(&sA[buf][((wm * 4 + 1) * 4 + kq) * 512 + lane * 8]);
      bf16x8 a2 = ld_frag(&sA[buf][((wm * 4 + 2) * 4 + kq) * 512 + lane * 8]);
      bf16x8 a3 = ld_frag(&sA[buf][((wm * 4 + 3) * 4 + kq) * 512 + lane * 8]);
      bf16x8 vg = ld_frag(&sBg[buf][(wn * 4 + kq) * 512 + lane * 8]);
      bf16x8 vu = ld_frag(&sBu[buf][(wn * 4 + kq) * 512 + lane * 8]);
      accg[0] = __builtin_amdgcn_mfma_f32_32x32x16_bf16(a0, vg, accg[0], 0, 0, 0);
      accg[1] = __builtin_amdgcn_mfma_f32_32x32x16_bf16(a1, vg, accg[1], 0, 0, 0);
      accg[2] = __builtin_amdgcn_mfma_f32_32x32x16_bf16(a2, vg, accg[2], 0, 0, 0);
      accg[3] = __builtin_amdgcn_mfma_f32_32x32x16_bf16(a3, vg, accg[3], 0, 0, 0);
      accu[0] = __builtin_amdgcn_mfma_f32_32x32x16_bf16(a0, vu, accu[0], 0, 0, 0);
      accu[1] = __builtin_amdgcn_mfma_f32_32x32x16_bf16(a1, vu, accu[1], 0, 0, 0);
      accu[2] = __builtin_amdgcn_mfma_f32_32x32x16_bf16(a2, vu, accu[2], 0, 0, 0);
      accu[3] = __builtin_amdgcn_mfma_f32_32x32x16_bf16(a3, vu, accu[3], 0, 0, 0);
    }
  };

  int cur = 0;
  stage(0, 0);
  if constexpr (PRE) {
#pragma unroll 2
    for (int ks = 0; ks < DMODEL / 64; ++ks) {
      if (ks + 1 < DMODEL / 64) {
        stage(cur ^ 1, ks + 1);
        asm volatile("s_waitcnt vmcnt(8)" ::: "memory");   // tile ks landed; ks+1 in flight
      } else {
        asm volatile("s_waitcnt vmcnt(0)" ::: "memory");   // final tile
      }
      __builtin_amdgcn_s_barrier();
      __builtin_amdgcn_s_setprio(1);
      compute(cur);
      __builtin_amdgcn_s_setprio(0);
      __builtin_amdgcn_s_barrier();                        // protect buf reuse; no drain
      cur ^= 1;
    }
  } else {
    __syncthreads();
    for (int ks = 0; ks < DMODEL / 64; ++ks) {
      if (ks + 1 < DMODEL / 64) stage(cur ^ 1, ks + 1);
      compute(cur);
      __syncthreads();
      cur ^= 1;
    }
  }

  // epilogue: write h CHUNK-PACKED for k_down's A-stage.
  // value h[row0+lrow][col], col = n0 + wn*32 + l31; acc layout row=(r&3)+8*(r>>2)+4*lh.
  int ks2 = bx * 2 + (wn >> 1);
  int kq2 = ((wn & 1) << 1) + (l31 >> 4);
  int lh2 = (l31 >> 3) & 1;
  int jj = l31 & 7;
#pragma unroll
  for (int m = 0; m < 4; ++m) {
    size_t cbase = ((size_t)(rt * 32 + ks2) * 32 + (wm * 4 + m) * 4 + kq2) * 512;
#pragma unroll
    for (int r = 0; r < 16; ++r) {
      int l31p = (r & 3) + ((r >> 2) << 3) + lh * 4;
      float gv = accg[m][r], uv = accu[m][r];
      float hv = gv * uv / (1.f + __expf(-gv));
      h[cbase + (size_t)(l31p + 32 * lh2) * 8 + jj] = f2bf(hv);
    }
  }
}

// ---------------- down GEMM: pv = h @ Wd^T, tile 256x128, BK=64, counted vmcnt -----
// A (h2) and B (wdb2) both chunk-packed -> contiguous 1KB global_load_lds.
template <bool PRE>
__global__ __launch_bounds__(512, 2) void k_down(
    const unsigned short* __restrict__ h, const float* __restrict__ wd32,
    const unsigned short* __restrict__ wdb, float* __restrict__ out,
    float* __restrict__ pv, const int* __restrict__ meta,
    const int* __restrict__ ptok, const float* __restrict__ pw) {
  int p = blockIdx.x;
  int xcd = p & 7, slot = p >> 3;                 // 40 slots per XCD
  int bx = slot & 7;
  int rt = xcd * 5 + (slot >> 3);

  int nt = meta[IDX_NT];
  if (rt >= nt) return;
  int e = meta[IDX_TE + rt];
  int row0 = meta[IDX_TR + rt];
  int d0 = bx * 128;

  __shared__ __align__(16) unsigned short sA[2][16384];   // 32 chunks
  __shared__ __align__(16) unsigned short sB[2][8192];    // 16 chunks
  __shared__ int stok[256];
  __shared__ float sw_[256];

  int tid = threadIdx.x, lane = tid & 63, w = tid >> 6;
  int wm = w & 1, wn = w >> 1;
  int l31 = lane & 31, lh = lane >> 5;

  if constexpr (!PRE) {
    if (tid < 256) { stok[tid] = ptok[row0 + tid]; sw_[tid] = pw[row0 + tid]; }
  }

  f32x16 acc[4];
#pragma unroll
  for (int m = 0; m < 4; ++m) {
#pragma unroll
    for (int r = 0; r < 16; ++r) acc[m][r] = 0.f;
  }

  const unsigned short* A0 =
      h + (((size_t)rt * 32) * 32 + w * 4) * 512 + (size_t)lane * 8;
  int cb0 = w * 2, cb1 = cb0 + 1;
  const unsigned short* B0;
  if constexpr (PRE) {
    B0 = wdb + (((size_t)(e * 8 + bx) * 32) * 16 + cb0) * 512 + (size_t)lane * 8;
  }
  const float* Wd = nullptr;
  if constexpr (!PRE) Wd = wd32 + (size_t)e * DMODEL * FDIM;

  auto stage = [&](int buf, int ks) {
    size_t ao = (size_t)ks * 16384;
    async_load16(A0 + ao,        &sA[buf][(w * 4 + 0) * 512]);
    async_load16(A0 + ao + 512,  &sA[buf][(w * 4 + 1) * 512]);
    async_load16(A0 + ao + 1024, &sA[buf][(w * 4 + 2) * 512]);
    async_load16(A0 + ao + 1536, &sA[buf][(w * 4 + 3) * 512]);
    if constexpr (PRE) {
      size_t bo = (size_t)ks * 8192;
      async_load16(B0 + bo,       &sB[buf][cb0 * 512]);
      async_load16(B0 + bo + 512, &sB[buf][cb1 * 512]);
    } else {
      int k0 = ks * 64;
#pragma unroll
      for (int i2 = 0; i2 < 2; ++i2) {
        int tau = tid + 512 * i2;
        int c = tau >> 6, l = tau & 63;
        int drow = d0 + ((c >> 2) << 5) + (l & 31);
        int kk = k0 + ((c & 3) << 4) + ((l >> 5) << 3);
        const float* sd = Wd + (size_t)drow * FDIM + kk;
        float4 b0 = *(const float4*)sd;
        float4 b1 = *(const float4*)(sd + 4);
        u16x8 vb = {f2bf(b0.x), f2bf(b0.y), f2bf(b0.z), f2bf(b0.w),
                    f2bf(b1.x), f2bf(b1.y), f2bf(b1.z), f2bf(b1.w)};
        *(u16x8*)&sB[buf][c * 512 + l * 8] = vb;
      }
    }
  };

  auto compute = [&](int buf) {
#pragma unroll
    for (int kq = 0; kq < 4; ++kq) {
      bf16x8 a0 = ld_frag(&sA[buf][((wm * 4 + 0) * 4 + kq) * 512 + lane * 8]);
      bf16x8 a1 = ld_frag(&sA[buf][((wm * 4 + 1) * 4 + kq) * 512 + lane * 8]);
      bf16x8 a2 = ld_frag(&sA[buf][((wm * 4 + 2) * 4 + kq) * 512 + lane * 8]);
      bf16x8 a3 = ld_frag(&sA[buf][((wm * 4 + 3) * 4 + kq) * 512 + lane * 8]);
      bf16x8 vb = ld_frag(&sB[buf][(wn * 4 + kq) * 512 + lane * 8]);
      acc[0] = __builtin_amdgcn_mfma_f32_32x32x16_bf16(a0, vb, acc[0], 0, 0, 0);
      acc[1] = __builtin_amdgcn_mfma_f32_32x32x16_bf16(a1, vb, acc[1], 0, 0, 0);
      acc[2] = __builtin_amdgcn_mfma_f32_32x32x16_bf16(a2, vb, acc[2], 0, 0, 0);
      acc[3] = __builtin_amdgcn_mfma_f32_32x32x16_bf16(a3, vb, acc[3], 0, 0, 0);
    }
  };

  int cur = 0;
  stage(0, 0);
  if constexpr (PRE) {
#pragma unroll 2
    for (int ks = 0; ks < FDIM / 64; ++ks) {
      if (ks + 1 < FDIM / 64) {
        stage(cur ^ 1, ks + 1);
        asm volatile("s_waitcnt vmcnt(6)" ::: "memory");   // tile ks landed; ks+1 in flight
      } else {
        asm volatile("s_waitcnt vmcnt(0)" ::: "memory");
      }
      __builtin_amdgcn_s_barrier();
      __builtin_amdgcn_s_setprio(1);
      compute(cur);
      __builtin_amdgcn_s_setprio(0);
      __builtin_amdgcn_s_barrier();
      cur ^= 1;
    }
  } else {
    __syncthreads();
    for (int ks = 0; ks < FDIM / 64; ++ks) {
      if (ks + 1 < FDIM / 64) stage(cur ^ 1, ks + 1);
      compute(cur);
      __syncthreads();
      cur ^= 1;
    }
  }

  int col = d0 + wn * 32 + l31;
#pragma unroll
  for (int m = 0; m < 4; ++m) {
#pragma unroll
    for (int r = 0; r < 16; ++r) {
      int lrow = wm * 128 + m * 32 + (r & 3) + ((r >> 2) << 3) + lh * 4;
      if constexpr (PRE) {
        pv[(size_t)(row0 + lrow) * DMODEL + col] = acc[m][r];
      } else {
        int t = stok[lrow];
        if (t >= 0) atomicAdd(&out[(size_t)t * DMODEL + col], acc[m][r] * sw_[lrow]);
      }
    }
  }
}

// ---------------- combine: out[t] = w1*pv[r1] + w2*pv[r2] --------------------------
__global__ void k_combine(const float* __restrict__ pv, const int* __restrict__ rpos,
                          const float* __restrict__ tkw, float* __restrict__ out) {
  int t = blockIdx.x;
  int r1 = rpos[2 * t], r2 = rpos[2 * t + 1];
  float w1 = tkw[2 * t], w2 = tkw[2 * t + 1];
  int c = threadIdx.x << 2;
  float4 a = *(const float4*)(pv + (size_t)r1 * DMODEL + c);
  float4 b = *(const float4*)(pv + (size_t)r2 * DMODEL + c);
  float4 o;
  o.x = w1 * a.x + w2 * b.x;
  o.y = w1 * a.y + w2 * b.y;
  o.z = w1 * a.z + w2 * b.z;
  o.w = w1 * a.w + w2 * b.w;
  *(float4*)(out + (size_t)t * DMODEL + c) = o;
}

// ---------------- launch ----------------
extern "C" void kernel_launch(void* const* d_in, const int* in_sizes, int n_in,
                              void* d_out, int out_size, void* d_ws, size_t ws_size,
                              hipStream_t stream) {
  const float* x  = (const float*)d_in[0];
  const float* gw = (const float*)d_in[1];
  const float* wg = (const float*)d_in[2];
  const float* wu = (const float*)d_in[3];
  const float* wd = (const float*)d_in[4];
  float* out = (float*)d_out;
  float* logits = out + OUT_MAIN;

  char* wsb = (char*)d_ws;
  int* meta = (int*)(wsb + OFF_META);
  float* tk_w = (float*)(wsb + OFF_TKW);
  int* ptok = (int*)(wsb + OFF_PTOK);
  float* pw = (float*)(wsb + OFF_PW);
  unsigned short* xg = (unsigned short*)(wsb + OFF_XG);
  unsigned short* h = (unsigned short*)(wsb + OFF_H);
  unsigned short* wgb = (unsigned short*)(wsb + OFF_WGB);
  unsigned short* wub = (unsigned short*)(wsb + OFF_WUB);
  unsigned short* wdb = (unsigned short*)(wsb + OFF_WDB);
  float* pv = (float*)(wsb + OFF_PV);
  int* rpos = (int*)(wsb + OFF_RPOS);

  bool pre = ws_size >= (size_t)WS_NEED;
  if (!pre) hipMemsetAsync(out, 0, (size_t)OUT_MAIN * sizeof(float), stream);

  k_prep<<<41984, 256, 0, stream>>>(wg, wu, wd, wgb, wub, wdb, x, gw, logits, (int)pre);
  k_route2<<<1, 1024, 0, stream>>>(logits, meta, tk_w, ptok, pw, rpos);
  k_gather<<<MAXP, 128, 0, stream>>>(x, ptok, xg);
  if (pre) {
    k_gu<true><<<(FDIM / 128) * MAXT, 512, 0, stream>>>(xg, wg, wu, wgb, wub, h, meta);
    k_down<true><<<(DMODEL / 128) * MAXT, 512, 0, stream>>>(h, wd, wdb, out, pv, meta, ptok, pw);
    k_combine<<<TOK, 256, 0, stream>>>(pv, rpos, tk_w, out);
  } else {
    k_gu<false><<<(FDIM / 128) * MAXT, 512, 0, stream>>>(xg, wg, wu, wgb, wub, h, meta);
    k_down<false><<<(DMODEL / 128) * MAXT, 512, 0, stream>>>(h, wd, wdb, out, pv, meta, ptok, pw);
  }
}